// Round 4
// baseline (98.759 us; speedup 1.0000x reference)
//
#include <hip/hip_runtime.h>

// Inverse Haar wavelet 2D:
//   x:       [B=16, 4C=256, H=128, W=128]  fp32
//   filters: [4C, 1, 2, 2] -> viewed as [C,4,2,2] fp32 (Haar +-1 taps)
//   out:     [B, C=64, 2H=256, 2W=256]     fp32
// out[b][c][2h+p][2w+q] = sum_k x[b][4c+k][h][w] * f[c][k][p][q]
//
// Memory-bound: 268 MB in + 268 MB out. One thread per (b,c,h,w_quad):
// 4x coalesced float4 loads (one per subband plane), 4x float4 stores
// (2 contiguous per output row).

#define BB 16
#define CC 64
#define HH 128
#define WW 128
#define W4 (WW / 4)                       // 32 quads per row
#define TOTAL (BB * CC * HH * W4)         // 4,194,304 threads

__global__ __launch_bounds__(256) void ihaar2d_kernel(
    const float* __restrict__ x,
    const float* __restrict__ filt,
    float* __restrict__ out)
{
    const int tid = blockIdx.x * blockDim.x + threadIdx.x;
    if (tid >= TOTAL) return;

    const int w4 = tid & (W4 - 1);        // 5 bits
    const int h  = (tid >> 5) & (HH - 1); // 7 bits
    const int c  = (tid >> 12) & (CC - 1);// 6 bits
    const int b  = tid >> 18;

    // ---- load 4 subband rows (k = 0..3), 4 consecutive w each ----
    const int plane = HH * WW;
    const float* xb = x + ((b * (4 * CC) + c * 4) * HH + h) * WW + w4 * 4;
    const float4 x0 = *(const float4*)(xb + 0 * plane);
    const float4 x1 = *(const float4*)(xb + 1 * plane);
    const float4 x2 = *(const float4*)(xb + 2 * plane);
    const float4 x3 = *(const float4*)(xb + 3 * plane);

    // ---- per-channel filter taps: f[c][k][p][q] at filt[c*16 + k*4 + p*2 + q]
    const float4* f4 = (const float4*)(filt + c * 16);
    const float4 f0 = f4[0];  // k=0: {p0q0, p0q1, p1q0, p1q1}
    const float4 f1 = f4[1];
    const float4 f2 = f4[2];
    const float4 f3 = f4[3];

    // ---- recombine: for each w, out2x2[p][q] = sum_k xk * fk[p][q] ----
    float r0[8], r1[8];   // row (2h) and row (2h+1), 8 contiguous outputs each
#define IHAAR_COMP(i, A, Bv, Cv, D)                                     \
    {                                                                   \
        r0[2*i + 0] = A * f0.x + Bv * f1.x + Cv * f2.x + D * f3.x;      \
        r0[2*i + 1] = A * f0.y + Bv * f1.y + Cv * f2.y + D * f3.y;      \
        r1[2*i + 0] = A * f0.z + Bv * f1.z + Cv * f2.z + D * f3.z;      \
        r1[2*i + 1] = A * f0.w + Bv * f1.w + Cv * f2.w + D * f3.w;      \
    }
    IHAAR_COMP(0, x0.x, x1.x, x2.x, x3.x)
    IHAAR_COMP(1, x0.y, x1.y, x2.y, x3.y)
    IHAAR_COMP(2, x0.z, x1.z, x2.z, x3.z)
    IHAAR_COMP(3, x0.w, x1.w, x2.w, x3.w)
#undef IHAAR_COMP

    // ---- store: two output rows, 8 floats each (2x float4, contiguous) ----
    const int OW = 2 * WW;                 // 256
    float* ob0 = out + ((b * CC + c) * (2 * HH) + 2 * h) * OW + w4 * 8;
    float* ob1 = ob0 + OW;
    ((float4*)ob0)[0] = make_float4(r0[0], r0[1], r0[2], r0[3]);
    ((float4*)ob0)[1] = make_float4(r0[4], r0[5], r0[6], r0[7]);
    ((float4*)ob1)[0] = make_float4(r1[0], r1[1], r1[2], r1[3]);
    ((float4*)ob1)[1] = make_float4(r1[4], r1[5], r1[6], r1[7]);
}

extern "C" void kernel_launch(void* const* d_in, const int* in_sizes, int n_in,
                              void* d_out, int out_size, void* d_ws, size_t ws_size,
                              hipStream_t stream) {
    const float* x    = (const float*)d_in[0];
    const float* filt = (const float*)d_in[1];
    float* out        = (float*)d_out;

    const int threads = 256;
    const int blocks  = (TOTAL + threads - 1) / threads;  // 16384
    ihaar2d_kernel<<<blocks, threads, 0, stream>>>(x, filt, out);
}